// Round 2
// baseline (579.737 us; speedup 1.0000x reference)
//
#include <hip/hip_runtime.h>

// Problem constants
#define Bb 16
#define Nn 16384
#define Ll 192
#define Ee 128
#define Dd 128

// Output element offsets (fp32 elements) within d_out:
// obs:     0          (16*16384*128 = 33554432)
// temp_he: 33554432   (16*192*128   =   393216)
// out:     33947648   (16*128*128   =   262144)
// ti:      34209792   (16*192*16384 = 50331648)
// vi:      84541440   (16*128*16384 = 33554432)   [ti+vi contiguous: 335.5 MB]

// ---------------------------------------------------------------------------
// k_main grid layout (4736 blocks x 256 threads) — fillBuffer-shaped:
//   [    0,  128): qkv  — q,kT,v = relu(var_w) @ W_{q,k,v} + b
//   [  128,  640): temp — sin(mark*Wt + bt), grid-stride ×3, NT stores
//   [  640, 2688): fill — ti+vi zero-stream, grid-stride ×40, NT stores
//                         (all in-flight stores live in an 8 MB moving window)
//   [ 2688, 4736): obs  — relu(feats @ W_obs + b_obs) * mask, ×16, NT stores
// Long-lived blocks keep deep per-wave store queues (the fillBufferAligned
// shape that demonstrably hits 6.1 TB/s); NT avoids L2/MALL write-allocate.
// ---------------------------------------------------------------------------
#define QKV_NB   128
#define TEMP_NB  512
#define FILL_NB  2048
#define OBS_NB   2048
#define TEMP_B0  (QKV_NB)               // 128
#define FILL_B0  (TEMP_B0 + TEMP_NB)    // 640
#define OBS_B0   (FILL_B0 + FILL_NB)    // 2688
#define GRID1    (OBS_B0 + OBS_NB)      // 4736

#define FILL_LANES (FILL_NB * 256)      // 524288
#define OBS_LANES  (OBS_NB * 256)       // 524288
#define TEMP_LANES (TEMP_NB * 256)      // 131072

using f4 = __attribute__((ext_vector_type(4))) float;

__global__ __launch_bounds__(256) void k_main(
    const float* __restrict__ var_w,
    const float* __restrict__ Wq, const float* __restrict__ bq,
    const float* __restrict__ Wk, const float* __restrict__ bk,
    const float* __restrict__ Wv, const float* __restrict__ bv,
    const float* __restrict__ x, const float* __restrict__ mask,
    const float* __restrict__ ymask,
    const float* __restrict__ W_obs, const float* __restrict__ b_obs,
    const float* __restrict__ mark, const float* __restrict__ Wt,
    const float* __restrict__ bt,
    float* __restrict__ zfill,          // = ti base; ti+vi contiguous
    float* __restrict__ q, float* __restrict__ kT, float* __restrict__ v,
    float* __restrict__ obs, float* __restrict__ temp)
{
    __shared__ float sh[Dd];
    const int tid = threadIdx.x;
    const unsigned bx = blockIdx.x;

    if (bx >= OBS_B0) {
        // obs: 16 grid-stride iterations; d is loop-invariant per lane so the
        // three W_obs/b_obs float4 loads hoist out of the loop.
        const unsigned lane = (bx - OBS_B0) * 256 + tid;
        const int d = (lane & 31) << 2;

        const float4 w0 = *reinterpret_cast<const float4*>(W_obs + d);
        const float4 w1 = *reinterpret_cast<const float4*>(W_obs + Dd + d);
        const float4 bb = *reinterpret_cast<const float4*>(b_obs + d);

        #pragma unroll 4
        for (int i = 0; i < 16; ++i) {
            const unsigned idx = lane + (unsigned)i * OBS_LANES;
            const int row = idx >> 5;

            const float m  = mask[row];
            const float xv = x[row];
            const float f1 = 1.0f - m + ymask[row];

            f4 o;
            o.x = fmaxf(fmaf(xv, w0.x, fmaf(f1, w1.x, bb.x)), 0.0f) * m;
            o.y = fmaxf(fmaf(xv, w0.y, fmaf(f1, w1.y, bb.y)), 0.0f) * m;
            o.z = fmaxf(fmaf(xv, w0.z, fmaf(f1, w1.z, bb.z)), 0.0f) * m;
            o.w = fmaxf(fmaf(xv, w0.w, fmaf(f1, w1.w, bb.w)), 0.0f) * m;
            __builtin_nontemporal_store(
                o, reinterpret_cast<f4*>(obs + ((size_t)row << 7) + d));
        }
    } else if (bx >= FILL_B0) {
        // zero-fill ti+vi: 40 grid-stride NT float4 stores per lane.
        f4* p = reinterpret_cast<f4*>(zfill);
        const size_t lane = (size_t)(bx - FILL_B0) * 256 + tid;
        const f4 z = {0.0f, 0.0f, 0.0f, 0.0f};
        #pragma unroll 8
        for (int i = 0; i < 40; ++i)
            __builtin_nontemporal_store(z, p + lane + (size_t)i * FILL_LANES);
    } else if (bx >= TEMP_B0) {
        const int lane = (bx - TEMP_B0) * 256 + tid;
        #pragma unroll
        for (int i = 0; i < 3; ++i) {
            const int idx = lane + i * TEMP_LANES;   // < 393216
            const int d = idx & 127;
            const int r = idx >> 7;
            __builtin_nontemporal_store(sinf(fmaf(mark[r], Wt[d], bt[d])),
                                        temp + idx);
        }
    } else {
        // qkv: one hyperedge row e per block, threads 0..127 active
        const int e = bx;
        if (tid < Dd) sh[tid] = fmaxf(var_w[e * Dd + tid], 0.0f);
        __syncthreads();
        if (tid < Dd) {
            float aq = bq[tid], ak = bk[tid], av = bv[tid];
            #pragma unroll 4
            for (int j = 0; j < Dd; ++j) {
                const float hj = sh[j];
                aq = fmaf(hj, Wq[j * Dd + tid], aq);
                ak = fmaf(hj, Wk[j * Dd + tid], ak);
                av = fmaf(hj, Wv[j * Dd + tid], av);
            }
            q[e * Dd + tid]  = aq;
            kT[tid * Dd + e] = ak;   // transposed for coalesced k_soft reads
            v[e * Dd + tid]  = av;
        }
    }
}

// ---------------------------------------------------------------------------
// k_scatter: runs after k_main (stream-ordered). Writes the ~2*131K one-hot
// nonzeros into the zeroed ti/vi planes and builds the per-(b,e) histogram
// partials (same cnt_part[256][128] layout k_soft expects: block = b*16+f).
// ---------------------------------------------------------------------------
__global__ __launch_bounds__(256) void k_scatter(
    const int* __restrict__ tidx, const int* __restrict__ vidx,
    const float* __restrict__ mask,
    float* __restrict__ ti, float* __restrict__ vi,
    float* __restrict__ cnt_part)
{
    __shared__ float sh[Ee];
    const int tid = threadIdx.x;
    const int g  = blockIdx.x * 256 + tid;   // 65536 threads over B*N/4
    const int b  = g >> 12;                  // 4096 threads per b
    const int n4 = (g & 4095) << 2;

    const int4   t4 = *reinterpret_cast<const int4*>(tidx + b * Nn + n4);
    const int4   v4 = *reinterpret_cast<const int4*>(vidx + b * Nn + n4);
    const float4 m4 = *reinterpret_cast<const float4*>(mask + b * Nn + n4);

    if (tid < Ee) sh[tid] = 0.0f;
    __syncthreads();

    float* tib = ti + (((size_t)b * Ll) << 14);
    float* vib = vi + (((size_t)b * Ee) << 14);

    if (m4.x != 0.0f) {
        atomicAdd(&sh[v4.x], 1.0f);
        tib[((size_t)t4.x << 14) + n4]     = m4.x;
        vib[((size_t)v4.x << 14) + n4]     = m4.x;
    }
    if (m4.y != 0.0f) {
        atomicAdd(&sh[v4.y], 1.0f);
        tib[((size_t)t4.y << 14) + n4 + 1] = m4.y;
        vib[((size_t)v4.y << 14) + n4 + 1] = m4.y;
    }
    if (m4.z != 0.0f) {
        atomicAdd(&sh[v4.z], 1.0f);
        tib[((size_t)t4.z << 14) + n4 + 2] = m4.z;
        vib[((size_t)v4.z << 14) + n4 + 2] = m4.z;
    }
    if (m4.w != 0.0f) {
        atomicAdd(&sh[v4.w], 1.0f);
        tib[((size_t)t4.w << 14) + n4 + 3] = m4.w;
        vib[((size_t)v4.w << 14) + n4 + 3] = m4.w;
    }

    __syncthreads();
    if (tid < Ee) cnt_part[blockIdx.x * Ee + tid] = sh[tid];
}

// ---------------------------------------------------------------------------
// k_soft (unchanged): per-(b,e) fused att-row, count reduction, diag merge,
// softmax, out = attn @ v.
// ---------------------------------------------------------------------------
__global__ __launch_bounds__(128) void k_soft(
    const float* __restrict__ q, const float* __restrict__ kT,
    const float* __restrict__ v, const float* __restrict__ cnt_part,
    const float* __restrict__ thr_p, const float* __restrict__ mc_p,
    const int* __restrict__ nobs_p, float* __restrict__ outp)
{
    __shared__ float qr[Dd];
    __shared__ float attn[Ee];
    __shared__ float red[5];
    const int b = blockIdx.x >> 7;
    const int e = blockIdx.x & 127;
    const int f = threadIdx.x;

    qr[f] = q[e * Dd + f];

    float cp = (f < 16) ? cnt_part[(b * 16 + f) * Ee + e] : 0.0f;
    #pragma unroll
    for (int off = 8; off > 0; off >>= 1) cp += __shfl_xor(cp, off);
    if (f == 0) red[4] = cp;
    __syncthreads();

    float acc0 = 0.0f;
    #pragma unroll 4
    for (int d = 0; d < Dd; ++d) acc0 = fmaf(qr[d], kT[d * Dd + f], acc0);
    float a = acc0 * 0.08838834764831845f;   // 1/sqrt(128)

    if (f == e) {
        const float c = red[4];
        const float thr = *thr_p;
        if (c != 0.0f && a > thr) {
            const float mc  = *mc_p;
            const float aux = c / sqrtf((float)(*nobs_p));
            a = (1.0f - mc) * a + mc * aux;
        }
    }

    float mx = a;
    #pragma unroll
    for (int off = 32; off > 0; off >>= 1) mx = fmaxf(mx, __shfl_xor(mx, off));
    if ((f & 63) == 0) red[f >> 6] = mx;
    __syncthreads();
    mx = fmaxf(red[0], red[1]);

    const float ex = expf(a - mx);
    float s = ex;
    #pragma unroll
    for (int off = 32; off > 0; off >>= 1) s += __shfl_xor(s, off);
    if ((f & 63) == 0) red[2 + (f >> 6)] = s;
    __syncthreads();
    s = red[2] + red[3];

    attn[f] = ex / s;
    __syncthreads();

    const int d = f;
    float acc = 0.0f;
    #pragma unroll 4
    for (int j = 0; j < Ee; ++j) acc = fmaf(attn[j], v[j * Dd + d], acc);
    outp[((size_t)(b * Ee + e) << 7) + d] = acc;
}

// ---------------------------------------------------------------------------
extern "C" void kernel_launch(void* const* d_in, const int* in_sizes, int n_in,
                              void* d_out, int out_size, void* d_ws, size_t ws_size,
                              hipStream_t stream) {
    (void)in_sizes; (void)n_in; (void)out_size; (void)ws_size;

    const float* x      = (const float*)d_in[0];
    const float* mask   = (const float*)d_in[1];
    const float* ymask  = (const float*)d_in[2];
    const float* mark   = (const float*)d_in[3];
    const int*   vidx   = (const int*)d_in[4];
    const int*   tidx   = (const int*)d_in[5];
    const int*   nobs   = (const int*)d_in[6];
    const float* W_obs  = (const float*)d_in[7];
    const float* b_obs  = (const float*)d_in[8];
    const float* W_time = (const float*)d_in[9];
    const float* b_time = (const float*)d_in[10];
    const float* var_w  = (const float*)d_in[11];
    const float* W_q    = (const float*)d_in[12];
    const float* b_q    = (const float*)d_in[13];
    const float* W_k    = (const float*)d_in[14];
    const float* b_k    = (const float*)d_in[15];
    const float* W_v    = (const float*)d_in[16];
    const float* b_v    = (const float*)d_in[17];
    const float* thr    = (const float*)d_in[18];
    const float* mc     = (const float*)d_in[19];

    float* out_base = (float*)d_out;
    float* obs  = out_base;
    float* temp = out_base + 33554432;
    float* attO = out_base + 33947648;
    float* ti   = out_base + 34209792;
    float* vi   = out_base + 84541440;

    // ws layout (fp32): cnt_part[256*128] | q[16384] | kT[16384] | v[16384]
    float* ws       = (float*)d_ws;
    float* cnt_part = ws;
    float* q        = ws + 32768;
    float* kT       = ws + 49152;
    float* v        = ws + 65536;

    k_main<<<GRID1, 256, 0, stream>>>(var_w,
                                      W_q, b_q, W_k, b_k, W_v, b_v,
                                      x, mask, ymask, W_obs, b_obs,
                                      mark, W_time, b_time,
                                      ti /* zfill base: ti+vi contiguous */,
                                      q, kT, v, obs, temp);
    k_scatter<<<256, 256, 0, stream>>>(tidx, vidx, mask, ti, vi, cnt_part);
    k_soft<<<Bb * Ee, Dd, 0, stream>>>(q, kT, v, cnt_part, thr, mc, nobs, attO);
}

// Round 3
// 567.102 us; speedup vs baseline: 1.0223x; 1.0223x over previous
//
#include <hip/hip_runtime.h>

// Problem constants
#define Bb 16
#define Nn 16384
#define Ll 192
#define Ee 128
#define Dd 128

// Output element offsets (fp32 elements) within d_out:
// obs:     0          (16*16384*128 = 33554432)
// temp_he: 33554432   (16*192*128   =   393216)
// out:     33947648   (16*128*128   =   262144)
// ti:      34209792   (16*192*16384 = 50331648)
// vi:      84541440   (16*128*16384 = 33554432)

// ---------------------------------------------------------------------------
// k_main grid layout (7808 blocks x 256 threads):
//   [    0, 5120): planes — one block per (b, plane) of ti/vi. Block reads its
//                  b's tidx-or-vidx + mask (192 KB/b, L2-resident across the
//                  320 plane-blocks of that b; ~3 MB HBM total) and writes its
//                  full 64 KB plane CONTIGUOUSLY with ones embedded — dense,
//                  no zero+scatter split. vi-blocks also block-reduce their
//                  match count -> cnt[b*128+e] directly (k_scatter eliminated).
//   [ 5120, 7168): obs  — relu(feats @ W_obs + b_obs) * mask, grid-stride x16
//   [ 7168, 7680): temp — sin(mark*Wt + bt), grid-stride x3
//   [ 7680, 7808): qkv  — q,kT,v = relu(var_w) @ W_{q,k,v} + b
// All stores regular (NT refuted in r2).
// ---------------------------------------------------------------------------
#define PLN_NB   5120
#define OBS_NB   2048
#define TEMP_NB  512
#define QKV_NB   128
#define OBS_B0   (PLN_NB)               // 5120
#define TEMP_B0  (OBS_B0 + OBS_NB)      // 7168
#define QKV_B0   (TEMP_B0 + TEMP_NB)    // 7680
#define GRID1    (QKV_B0 + QKV_NB)      // 7808

#define OBS_LANES  (OBS_NB * 256)       // 524288
#define TEMP_LANES (TEMP_NB * 256)      // 131072

__global__ __launch_bounds__(256) void k_main(
    const int* __restrict__ tidx, const int* __restrict__ vidx,
    const float* __restrict__ mask, const float* __restrict__ var_w,
    const float* __restrict__ Wq, const float* __restrict__ bq,
    const float* __restrict__ Wk, const float* __restrict__ bk,
    const float* __restrict__ Wv, const float* __restrict__ bv,
    const float* __restrict__ x, const float* __restrict__ ymask,
    const float* __restrict__ W_obs, const float* __restrict__ b_obs,
    const float* __restrict__ mark, const float* __restrict__ Wt,
    const float* __restrict__ bt,
    float* __restrict__ ti, float* __restrict__ vi,
    float* __restrict__ cnt,            // [16][128] direct counts
    float* __restrict__ q, float* __restrict__ kT, float* __restrict__ v,
    float* __restrict__ obs, float* __restrict__ temp)
{
    __shared__ float sh[Dd];
    __shared__ float rr[4];
    const int tid = threadIdx.x;
    const unsigned bx = blockIdx.x;

    if (bx < PLN_NB) {
        // one (b, plane): 256 threads x 16 float4 = 16384 elements = 64 KB
        const int b     = bx / 320;
        const int pl    = bx - b * 320;
        const bool isti = (pl < Ll);
        const int plane = isti ? pl : pl - Ll;

        const int*   ib = (isti ? tidx : vidx) + b * Nn;
        const float* mb = mask + b * Nn;
        float* op = isti ? (ti + (((size_t)(b * Ll + plane)) << 14))
                         : (vi + (((size_t)(b * Ee + plane)) << 14));

        float c = 0.0f;
        #pragma unroll 4
        for (int i = 0; i < 16; ++i) {
            const int n4 = ((i << 8) + tid) << 2;   // wave: 1 KB contiguous
            const int4   t4 = *reinterpret_cast<const int4*>(ib + n4);
            const float4 m4 = *reinterpret_cast<const float4*>(mb + n4);
            float4 o;
            o.x = (t4.x == plane) ? m4.x : 0.0f;
            o.y = (t4.y == plane) ? m4.y : 0.0f;
            o.z = (t4.z == plane) ? m4.z : 0.0f;
            o.w = (t4.w == plane) ? m4.w : 0.0f;
            *reinterpret_cast<float4*>(op + n4) = o;
            c += (o.x + o.y) + (o.z + o.w);   // mask is {0,1}: sum == count
        }

        if (!isti) {   // block-uniform branch
            #pragma unroll
            for (int off = 32; off > 0; off >>= 1) c += __shfl_xor(c, off);
            if ((tid & 63) == 0) rr[tid >> 6] = c;
            __syncthreads();
            if (tid == 0)
                cnt[b * Ee + plane] = (rr[0] + rr[1]) + (rr[2] + rr[3]);
        }
    } else if (bx < TEMP_B0) {
        // obs: 16 grid-stride iterations; W-rows hoisted (d loop-invariant)
        const unsigned lane = (bx - OBS_B0) * 256 + tid;
        const int d = (lane & 31) << 2;

        const float4 w0 = *reinterpret_cast<const float4*>(W_obs + d);
        const float4 w1 = *reinterpret_cast<const float4*>(W_obs + Dd + d);
        const float4 bb = *reinterpret_cast<const float4*>(b_obs + d);

        #pragma unroll 4
        for (int i = 0; i < 16; ++i) {
            const unsigned idx = lane + (unsigned)i * OBS_LANES;
            const int row = idx >> 5;

            const float m  = mask[row];
            const float xv = x[row];
            const float f1 = 1.0f - m + ymask[row];

            float4 o;
            o.x = fmaxf(fmaf(xv, w0.x, fmaf(f1, w1.x, bb.x)), 0.0f) * m;
            o.y = fmaxf(fmaf(xv, w0.y, fmaf(f1, w1.y, bb.y)), 0.0f) * m;
            o.z = fmaxf(fmaf(xv, w0.z, fmaf(f1, w1.z, bb.z)), 0.0f) * m;
            o.w = fmaxf(fmaf(xv, w0.w, fmaf(f1, w1.w, bb.w)), 0.0f) * m;
            *reinterpret_cast<float4*>(obs + ((size_t)row << 7) + d) = o;
        }
    } else if (bx < QKV_B0) {
        const int lane = (bx - TEMP_B0) * 256 + tid;
        #pragma unroll
        for (int i = 0; i < 3; ++i) {
            const int idx = lane + i * TEMP_LANES;   // < 393216
            const int d = idx & 127;
            const int r = idx >> 7;
            temp[idx] = sinf(fmaf(mark[r], Wt[d], bt[d]));
        }
    } else {
        // qkv: one hyperedge row e per block, threads 0..127 active
        const int e = bx - QKV_B0;
        if (tid < Dd) sh[tid] = fmaxf(var_w[e * Dd + tid], 0.0f);
        __syncthreads();
        if (tid < Dd) {
            float aq = bq[tid], ak = bk[tid], av = bv[tid];
            #pragma unroll 4
            for (int j = 0; j < Dd; ++j) {
                const float hj = sh[j];
                aq = fmaf(hj, Wq[j * Dd + tid], aq);
                ak = fmaf(hj, Wk[j * Dd + tid], ak);
                av = fmaf(hj, Wv[j * Dd + tid], av);
            }
            q[e * Dd + tid]  = aq;
            kT[tid * Dd + e] = ak;   // transposed for coalesced k_soft reads
            v[e * Dd + tid]  = av;
        }
    }
}

// ---------------------------------------------------------------------------
// k_soft: per-(b,e) fused att-row (q[e]·kT), diagonal merge-adjust (direct
// cnt read — no partials), softmax over f, out = attn @ v.
// ---------------------------------------------------------------------------
__global__ __launch_bounds__(128) void k_soft(
    const float* __restrict__ q, const float* __restrict__ kT,
    const float* __restrict__ v, const float* __restrict__ cnt,
    const float* __restrict__ thr_p, const float* __restrict__ mc_p,
    const int* __restrict__ nobs_p, float* __restrict__ outp)
{
    __shared__ float qr[Dd];
    __shared__ float attn[Ee];
    __shared__ float red[4];
    const int b = blockIdx.x >> 7;
    const int e = blockIdx.x & 127;
    const int f = threadIdx.x;

    qr[f] = q[e * Dd + f];
    __syncthreads();

    // att0[e,f] = dot(q[e], k[f]) / sqrt(D); kT read is lane-coalesced
    float acc0 = 0.0f;
    #pragma unroll 4
    for (int d = 0; d < Dd; ++d) acc0 = fmaf(qr[d], kT[d * Dd + f], acc0);
    float a = acc0 * 0.08838834764831845f;   // 1/sqrt(128)

    if (f == e) {
        const float c = cnt[b * Ee + e];
        const float thr = *thr_p;
        if (c != 0.0f && a > thr) {
            const float mc  = *mc_p;
            const float aux = c / sqrtf((float)(*nobs_p));
            a = (1.0f - mc) * a + mc * aux;
        }
    }

    // block max (2 waves)
    float mx = a;
    #pragma unroll
    for (int off = 32; off > 0; off >>= 1) mx = fmaxf(mx, __shfl_xor(mx, off));
    if ((f & 63) == 0) red[f >> 6] = mx;
    __syncthreads();
    mx = fmaxf(red[0], red[1]);

    const float ex = expf(a - mx);
    float s = ex;
    #pragma unroll
    for (int off = 32; off > 0; off >>= 1) s += __shfl_xor(s, off);
    if ((f & 63) == 0) red[2 + (f >> 6)] = s;
    __syncthreads();
    s = red[2] + red[3];

    attn[f] = ex / s;
    __syncthreads();

    const int d = f;
    float acc = 0.0f;
    #pragma unroll 4
    for (int j = 0; j < Ee; ++j) acc = fmaf(attn[j], v[j * Dd + d], acc);
    outp[((size_t)(b * Ee + e) << 7) + d] = acc;
}

// ---------------------------------------------------------------------------
extern "C" void kernel_launch(void* const* d_in, const int* in_sizes, int n_in,
                              void* d_out, int out_size, void* d_ws, size_t ws_size,
                              hipStream_t stream) {
    (void)in_sizes; (void)n_in; (void)out_size; (void)ws_size;

    const float* x      = (const float*)d_in[0];
    const float* mask   = (const float*)d_in[1];
    const float* ymask  = (const float*)d_in[2];
    const float* mark   = (const float*)d_in[3];
    const int*   vidx   = (const int*)d_in[4];
    const int*   tidx   = (const int*)d_in[5];
    const int*   nobs   = (const int*)d_in[6];
    const float* W_obs  = (const float*)d_in[7];
    const float* b_obs  = (const float*)d_in[8];
    const float* W_time = (const float*)d_in[9];
    const float* b_time = (const float*)d_in[10];
    const float* var_w  = (const float*)d_in[11];
    const float* W_q    = (const float*)d_in[12];
    const float* b_q    = (const float*)d_in[13];
    const float* W_k    = (const float*)d_in[14];
    const float* b_k    = (const float*)d_in[15];
    const float* W_v    = (const float*)d_in[16];
    const float* b_v    = (const float*)d_in[17];
    const float* thr    = (const float*)d_in[18];
    const float* mc     = (const float*)d_in[19];

    float* out_base = (float*)d_out;
    float* obs  = out_base;
    float* temp = out_base + 33554432;
    float* attO = out_base + 33947648;
    float* ti   = out_base + 34209792;
    float* vi   = out_base + 84541440;

    // ws layout (fp32): cnt[16*128] | q[16384] | kT[16384] | v[16384]
    float* ws  = (float*)d_ws;
    float* cnt = ws;
    float* q   = ws + 2048;
    float* kT  = ws + 2048 + 16384;
    float* v   = ws + 2048 + 32768;

    k_main<<<GRID1, 256, 0, stream>>>(tidx, vidx, mask, var_w,
                                      W_q, b_q, W_k, b_k, W_v, b_v,
                                      x, ymask, W_obs, b_obs,
                                      mark, W_time, b_time,
                                      ti, vi, cnt, q, kT, v, obs, temp);
    k_soft<<<Bb * Ee, Dd, 0, stream>>>(q, kT, v, cnt, thr, mc, nobs, attO);
}